// Round 12
// baseline (4127.741 us; speedup 1.0000x reference)
//
#include <hip/hip_runtime.h>

typedef unsigned int uint32;
typedef unsigned long long uint64;
typedef _Float16 f16;
typedef _Float16 half8 __attribute__((ext_vector_type(8)));
typedef float floatx4 __attribute__((ext_vector_type(4)));

#define HD    512    // hidden
#define NBAT  256    // batch
#define CTXL  512    // context length
#define NPRED 64     // prediction length
#define NBLK  256
#define NTHR  256
#define NSTR  4      // independent batch stripes (64 rows each)
#define LDS_BYTES (6*16*64*16)   // 98304 B: fragment-linear weights
#define NGEN  575u               // role-intervals per launch

// R17 (3788us): region-major h-state, sc1, load-back producer protocol.
// R24 (3563us, BEST): write-once step-indexed h-buffers + sc0 consumer reads.
// R25 FAILED PERF (+10%): agent-release RMW publish is SLOWER than the
// load-back protocol on gfx950 (scope-wide drain beats targeted proof).
// Publish reverted to R24's store -> sc1 load-back -> drain -> relaxed RMW.
// R26 (this round): HIERARCHICAL ARRIVAL SUMMARY to kill the poll storm.
// Old: every block polls 16 lines x 16 lanes of sc1 loads (256 blocks ->
// ~4096 concurrent scattered MALL requests, inflating every RT in the chain).
// New: per-line RMW unchanged (returns old value); the block that COMPLETES
// its line (old+1 == line target) RMWs a single per-stripe per-role SUMMARY
// word. Consumers poll that ONE word with ONE lane (256x less poll traffic).
// Sound: summary==16*(s+1) => all line-RMWs executed (MALL serializes same-
// address RMWs) => all loadback-proven stores committed.
__device__ __attribute__((aligned(256))) f16   g_h0s[NGEN+2][NSTR][32][64][16];
__device__ __attribute__((aligned(256))) f16   g_h1s[NGEN+2][NSTR][32][64][16];
__device__ __attribute__((aligned(256))) float g_yacc[NPRED][NBAT];
__device__ __attribute__((aligned(256))) float g_scale[NBAT];
// Per stripe: 16 lines (128B apart) per role; 2 blocks arrive per line per gen.
__device__ __attribute__((aligned(256))) uint32 g_alines[NSTR*16*32];
__device__ __attribute__((aligned(256))) uint32 g_blines[NSTR*16*32];
__device__ __attribute__((aligned(256))) uint32 g_ilines[NSTR*16*32];  // init, 4/line
__device__ __attribute__((aligned(256))) uint32 g_asum[NSTR*64];       // summary words
__device__ __attribute__((aligned(256))) uint32 g_bsum[NSTR*64];       // (256B apart)
__device__ __attribute__((aligned(256))) uint32 g_sepoch[NSTR*64];     // launch count

__device__ __forceinline__ float sigm(float x){ return 1.f/(1.f+__expf(-x)); }
__device__ __forceinline__ float tanh_(float x){ return 1.f - 2.f/(__expf(2.f*x)+1.f); }

// ---- device-coherent (sc1, MALL-direct) helpers ----------------------------
__device__ __forceinline__ uint32 ld_u32_dc(const uint32* p){
  return __hip_atomic_load(p, __ATOMIC_RELAXED, __HIP_MEMORY_SCOPE_AGENT);
}
__device__ __forceinline__ void st_u32_dc(uint32* p, uint32 v){
  __hip_atomic_store(p, v, __ATOMIC_RELAXED, __HIP_MEMORY_SCOPE_AGENT);
}
__device__ __forceinline__ void st_u64_dc(uint64* p, uint64 v){
  __hip_atomic_store(p, v, __ATOMIC_RELAXED, __HIP_MEMORY_SCOPE_AGENT);
}
__device__ __forceinline__ float ld_f32_dc(const float* p){
  return __hip_atomic_load(p, __ATOMIC_RELAXED, __HIP_MEMORY_SCOPE_AGENT);
}
__device__ __forceinline__ void st_f32_dc(float* p, float v){
  __hip_atomic_store(p, v, __ATOMIC_RELAXED, __HIP_MEMORY_SCOPE_AGENT);
}
__device__ __forceinline__ float ld_f16_dc(const f16* p){
  unsigned short u = __hip_atomic_load((const unsigned short*)p, __ATOMIC_RELAXED, __HIP_MEMORY_SCOPE_AGENT);
  union { unsigned short u; f16 h; } c; c.u = u; return (float)c.h;
}
__device__ __forceinline__ void st_f16_dc(f16* p, f16 h){
  union { unsigned short u; f16 h; } c; c.h = h;
  __hip_atomic_store((unsigned short*)p, c.u, __ATOMIC_RELAXED, __HIP_MEMORY_SCOPE_AGENT);
}
// ---- sc0 (L1-bypass, L2-FILL) consumer load: write-once addresses only -----
__device__ __forceinline__ void ld_b128_sc0(floatx4* d, const f16* p){
  asm volatile("global_load_dwordx4 %0, %1, off sc0" : "=v"(*d) : "v"(p));
}
#define VM_DRAIN() do { asm volatile("s_waitcnt vmcnt(0)":::"memory"); \
                        __builtin_amdgcn_sched_barrier(0); } while(0)

// Single-word summary wait: ONE lane polls ONE word (R26).
__device__ __forceinline__ void waitS(const uint32* sw, uint32 tgt){
  if (threadIdx.x < 64) {
    const int lane = threadIdx.x;
    for (;;) {
      bool ok = (lane != 0) || ((int)(ld_u32_dc(sw) - tgt) >= 0);
      if (__ballot(ok) == ~0ull) break;
      __builtin_amdgcn_s_sleep(1);
    }
  }
  __syncthreads();
}
// Init wait (16 lines, once per launch).
__device__ __forceinline__ void waitl(const uint32* lines, uint32 tgt){
  if (threadIdx.x < 64) {
    const int lane = threadIdx.x;
    const uint32* fp = &lines[(lane & 15)*32];
    for (;;) {
      bool ok = (lane >= 16) || ((int)(ld_u32_dc(fp) - tgt) >= 0);
      if (__ballot(ok) == ~0ull) break;
      __builtin_amdgcn_s_sleep(1);
    }
  }
  __syncthreads();
}
// Arrival with summary promotion (R26): drain block's stores+load-backs
// (fence+syncthreads), line RMW; the completer (old+1 == linedone) promotes
// to the stripe/role summary word with a second relaxed RMW.
__device__ __forceinline__ void arrive_sum(uint32* lines, int li, uint32 linedone,
                                           uint32* sump){
  __builtin_amdgcn_fence(__ATOMIC_RELEASE, "workgroup");
  __syncthreads();
  if (threadIdx.x == 0) {
    uint32 old = __hip_atomic_fetch_add(&lines[li*32], 1u,
                   __ATOMIC_RELAXED, __HIP_MEMORY_SCOPE_AGENT);
    if (old + 1u == linedone)
      __hip_atomic_fetch_add(sump, 1u,
                   __ATOMIC_RELAXED, __HIP_MEMORY_SCOPE_AGENT);
  }
}
__device__ __forceinline__ void arrive_rel(uint32* lines, int li){  // init only
  __builtin_amdgcn_fence(__ATOMIC_RELEASE, "workgroup");
  __syncthreads();
  if (threadIdx.x == 0)
    __hip_atomic_fetch_add(&lines[li*32], 1u, __ATOMIC_RELEASE, __HIP_MEMORY_SCOPE_AGENT);
}

// Persistent 2-layer GRU + AR decode; 4 independent 64-row stripes.
// Stripe s: blocks 64s..64s+63. rr<32: A (layer 0); rr>=32: B (layer 1).
// Weights in fragment-linear LDS. Region-major h-state:
// addr = region*1024 + row_local*16 + col; step t lives at buffer index t+1.
__global__ __launch_bounds__(NTHR, 1) void rnn_persist(
    const float* __restrict__ ctx,    // [256][512] f32
    const float* __restrict__ Wih0,   // [1536]
    const float* __restrict__ Whh0,   // [1536][512]
    const float* __restrict__ bih0,   // [1536]
    const float* __restrict__ bhh0,   // [1536]
    const float* __restrict__ Wih1,   // [1536][512]
    const float* __restrict__ Whh1,   // [1536][512]
    const float* __restrict__ bih1,   // [1536]
    const float* __restrict__ bhh1,   // [1536]
    const float* __restrict__ Wout,   // [512]
    const float* __restrict__ boutp,  // [1]
    float* __restrict__ out)          // [256][64] f32
{
  extern __shared__ char smem_raw[];
  f16* wlds = (f16*)smem_raw;
  __shared__ float wsum[4];

  const int tid  = threadIdx.x;
  const int bid  = blockIdx.x;
  const int sid  = bid >> 6;         // stripe
  const int rr_  = bid & 63;
  const bool isA = rr_ < 32;
  const int ng   = isA ? rr_ : rr_ - 32;
  const int Mbase = sid * 64;        // batch-row base of stripe
  const int s0    = ng * 16;         // hidden-col base of this block
  const int w    = tid >> 6;
  const int lane = tid & 63;
  const int quad = lane >> 4;
  const int l16  = lane & 15;

  uint32* al = &g_alines[sid*512];
  uint32* bl = &g_blines[sid*512];
  uint32* il = &g_ilines[sid*512];
  uint32* as_ = &g_asum[sid*64];
  uint32* bs_ = &g_bsum[sid*64];
  const uint32 E = ld_u32_dc(&g_sepoch[sid*64]);
  const uint32 baseA = E * (2u*NGEN);     // per-line bases
  const uint32 baseB = E * (2u*NGEN);
  const uint32 baseAS = E * (16u*NGEN);   // summary bases
  const uint32 baseBS = E * (16u*NGEN);

  // ---------------- init (stripe-local): scale, zero step-0 states ----------
  {
    const int b = bid;               // block bid handles batch row bid
    float s2 = 0.f;
    for (int k = tid; k < CTXL; k += NTHR) s2 += ctx[b*CTXL + k];
    #pragma unroll
    for (int m = 1; m < 64; m <<= 1) s2 += __shfl_xor(s2, m, 64);
    if (lane == 0) wsum[w] = s2;
    __syncthreads();
    float tot = wsum[0] + wsum[1] + wsum[2] + wsum[3];
    float sc  = fmaxf(fabsf(tot / (float)CTXL), 1e-5f);
    if (tid == 0) st_f32_dc(&g_scale[b], sc);
    // zero h0(-1) and h1(-1) at buffer index 0 (64 blocks x 128 u64 each)
    uint64* z0 = (uint64*)&g_h0s[0][sid][0][0][0];
    uint64* z1 = (uint64*)&g_h1s[0][sid][0][0][0];
    const int off = rr_*128;
    for (int k = tid; k < 128; k += NTHR) {
      st_u64_dc(z0+off+k, 0ull); st_u64_dc(z1+off+k, 0ull);
    }
    if (tid < 64) st_f32_dc(&g_yacc[rr_][Mbase + tid], 0.f);
  }

  // -------- weights -> fragment-linear LDS (f32 -> f16, conflict-free) ------
  {
    const int nfrag = isA ? (3*16*64) : (6*16*64);
    for (int idx = tid; idx < nfrag; idx += NTHR) {
      const int ln = idx & 63;
      const int kc = (idx >> 6) & 15;
      const int mg = idx >> 10;
      const float* Wsrc;
      int g;
      if (isA)            { Wsrc = Whh0; g = mg; }
      else if (mg < 3)    { Wsrc = Wih1; g = mg; }
      else                { Wsrc = Whh1; g = mg - 3; }
      const float* src = Wsrc + (size_t)(g*HD + s0 + (ln & 15))*HD + (ln >> 4)*8 + kc*32;
      f16* dst = wlds + (size_t)idx*8;
      #pragma unroll
      for (int j = 0; j < 8; ++j) dst[j] = (f16)src[j];
    }
  }

  // ---------------- per-thread constants ------------------------------------
  float wi_r=0, wi_z=0, wi_n=0, bi_r, bi_z, bi_n, bh_r, bh_z, bh_n;
  float woutj=0, boutv=0;
  const int jcol = s0 + l16;
  const int mf = w;                  // 4 waves x 16 batch rows = 64 rows
  if (isA) {
    wi_r = Wih0[jcol]; wi_z = Wih0[HD + jcol]; wi_n = Wih0[2*HD + jcol];
    bi_r = bih0[jcol]; bi_z = bih0[HD + jcol]; bi_n = bih0[2*HD + jcol];
    bh_r = bhh0[jcol]; bh_z = bhh0[HD + jcol]; bh_n = bhh0[2*HD + jcol];
  } else {
    bi_r = bih1[jcol]; bi_z = bih1[HD + jcol]; bi_n = bih1[2*HD + jcol];
    bh_r = bhh1[jcol]; bh_z = bhh1[HD + jcol]; bh_n = bhh1[2*HD + jcol];
    woutj = Wout[jcol]; boutv = boutp[0];
  }

  // region-major addressing constants
  const int rl0 = mf*16 + quad*4;    // first local row of my 4 output rows
  const int arl = mf*16 + l16;       // local row of my MFMA A-fragment
  const int own = ng*1024;           // my region base (elements)
  const size_t afrag = (size_t)(quad>>1)*1024 + (size_t)arl*16 + (quad&1)*8;
  const size_t SSTEP = (size_t)NSTR*32*64*16;   // elements per step index

  // strong init barrier (release arrival + agent acquire, once per launch).
  arrive_rel(il, rr_ & 15);
  waitl(il, E*4u + 4u);
  __builtin_amdgcn_fence(__ATOMIC_ACQUIRE, "agent");
  __syncthreads();

  // preload scale for my 4 output rows
  float scl[4];
  {
    const int bb = Mbase + rl0;
    #pragma unroll
    for (int reg = 0; reg < 4; ++reg) scl[reg] = ld_f32_dc(&g_scale[bb + reg]);
  }

  float chk = 0.f;     // load-back accumulator; guard below is never true
  float hold[4] = {0.f, 0.f, 0.f, 0.f};  // own-slice previous output (registers)

  // ---------------- role loops ----------------------------------------------
  if (isA) {
    const f16* h0base = &g_h0s[0][sid][0][0][0];
    for (int sA = 0; sA < (int)NGEN; ++sA) {
      const int b0 = Mbase + rl0;
      float xv[4];
      if (sA < 512) {                                // hoisted: ctx is read-only
        #pragma unroll
        for (int reg = 0; reg < 4; ++reg)
          xv[reg] = ctx[(b0+reg)*CTXL + sA] / scl[reg];
      }
      waitS(as_, baseAS + 16u*(uint32)sA);           // all A done sA-1 (summary)
      const f16* hrd = h0base + (size_t)sA*SSTEP;      // h0(sA-1) @ index sA
      f16*       hwr = (f16*)h0base + (size_t)(sA+1)*SSTEP;  // h0(sA)
      const f16* aptr = hrd + afrag;
      union { floatx4 f; half8 h; } av[16];
      #pragma unroll
      for (int kc = 0; kc < 16; ++kc)
        ld_b128_sc0(&av[kc].f, aptr + kc*2048);      // sc0: L2-fill, dedup'd
      if (sA >= 512) {
        waitS(bs_, baseBS + 16u*(uint32)sA);         // y(sA-512) ready (summary)
        #pragma unroll
        for (int reg = 0; reg < 4; ++reg)
          xv[reg] = ld_f32_dc(&g_yacc[sA-512][b0+reg]);
      }
      VM_DRAIN();
      floatx4 ar = {0.f,0.f,0.f,0.f}, az = ar, an_ = ar;
      const f16* fb = wlds + (size_t)lane*8;
      #pragma unroll
      for (int kc = 0; kc < 16; ++kc) {
        const f16* fkc = fb + (size_t)kc*512;
        half8 v;
        v = *(const half8*)(fkc);          ar  = __builtin_amdgcn_mfma_f32_16x16x32_f16(av[kc].h, v, ar,  0,0,0);
        v = *(const half8*)(fkc + 8192);   az  = __builtin_amdgcn_mfma_f32_16x16x32_f16(av[kc].h, v, az,  0,0,0);
        v = *(const half8*)(fkc + 16384);  an_ = __builtin_amdgcn_mfma_f32_16x16x32_f16(av[kc].h, v, an_, 0,0,0);
      }
      #pragma unroll
      for (int reg = 0; reg < 4; ++reg) {
        float hgr = ar[reg] + bh_r, hgz = az[reg] + bh_z, hgn = an_[reg] + bh_n;
        float rg  = sigm(fmaf(xv[reg], wi_r, bi_r) + hgr);
        float zg  = sigm(fmaf(xv[reg], wi_z, bi_z) + hgz);
        float ng_ = tanh_(fmaf(xv[reg], wi_n, bi_n) + rg*hgn);
        f16 hq = (f16)((1.f - zg)*ng_ + zg*hold[reg]);
        st_f16_dc(&hwr[own + (rl0+reg)*16 + l16], hq);
        hold[reg] = (float)hq;                       // carry rounded value
      }
      #pragma unroll
      for (int reg = 0; reg < 4; ++reg)        // load-backs prove commit
        chk += ld_f16_dc(&hwr[own + (rl0+reg)*16 + l16]);
      arrive_sum(al, rr_ & 15, baseA + 2u*(uint32)sA + 2u, as_);
    }
  } else {
    const f16* h0base = &g_h0s[0][sid][0][0][0];
    const f16* h1base = &g_h1s[0][sid][0][0][0];
    for (int sB = 0; sB < (int)NGEN; ++sB) {
      waitS(as_, baseAS + 16u*(uint32)(sB+1));       // h0(sB) published (summary)
      const f16* a0p = h0base + (size_t)(sB+1)*SSTEP + afrag;   // h0(sB)
      union { floatx4 f; half8 h; } a0v[16], a1v[16];
      #pragma unroll
      for (int kc = 0; kc < 16; ++kc)
        ld_b128_sc0(&a0v[kc].f, a0p + kc*2048);      // sc0: L2-fill
      waitS(bs_, baseBS + 16u*(uint32)sB);           // all B done sB-1 (summary)
      const f16* a1p = h1base + (size_t)sB*SSTEP + afrag;       // h1(sB-1)
      f16*       h1wr = (f16*)h1base + (size_t)(sB+1)*SSTEP;    // h1(sB)
      const int b0 = Mbase + rl0;
      #pragma unroll
      for (int kc = 0; kc < 16; ++kc)
        ld_b128_sc0(&a1v[kc].f, a1p + kc*2048);      // sc0: L2-fill
      VM_DRAIN();
      floatx4 xr = {0.f,0.f,0.f,0.f}, xz = xr, xn = xr, hr = xr, hz = xr, hn = xr;
      const f16* fb = wlds + (size_t)lane*8;
      #pragma unroll
      for (int kc = 0; kc < 16; ++kc) {
        const f16* fkc = fb + (size_t)kc*512;
        half8 v;
        v = *(const half8*)(fkc);           xr = __builtin_amdgcn_mfma_f32_16x16x32_f16(a0v[kc].h, v, xr, 0,0,0);
        v = *(const half8*)(fkc + 8192);    xz = __builtin_amdgcn_mfma_f32_16x16x32_f16(a0v[kc].h, v, xz, 0,0,0);
        v = *(const half8*)(fkc + 16384);   xn = __builtin_amdgcn_mfma_f32_16x16x32_f16(a0v[kc].h, v, xn, 0,0,0);
      }
      #pragma unroll
      for (int kc = 0; kc < 16; ++kc) {
        const f16* fkc = fb + (size_t)kc*512;
        half8 v;
        v = *(const half8*)(fkc + 24576);   hr = __builtin_amdgcn_mfma_f32_16x16x32_f16(a1v[kc].h, v, hr, 0,0,0);
        v = *(const half8*)(fkc + 32768);   hz = __builtin_amdgcn_mfma_f32_16x16x32_f16(a1v[kc].h, v, hz, 0,0,0);
        v = *(const half8*)(fkc + 40960);   hn = __builtin_amdgcn_mfma_f32_16x16x32_f16(a1v[kc].h, v, hn, 0,0,0);
      }
      #pragma unroll
      for (int reg = 0; reg < 4; ++reg) {
        const int b = b0 + reg;
        float rg  = sigm(xr[reg] + bi_r + hr[reg] + bh_r);
        float zg  = sigm(xz[reg] + bi_z + hz[reg] + bh_z);
        float ng_ = tanh_(xn[reg] + bi_n + rg*(hn[reg] + bh_n));
        float hnew = (1.f - zg)*ng_ + zg*hold[reg];
        f16 hq = (f16)hnew;
        st_f16_dc(&h1wr[own + (rl0+reg)*16 + l16], hq);
        hold[reg] = (float)hq;                       // carry rounded value
        if (sB >= 511) {                     // forecast partials, p = sB-511
          float c = hnew * woutj;
          c += __shfl_xor(c, 1, 64); c += __shfl_xor(c, 2, 64);
          c += __shfl_xor(c, 4, 64); c += __shfl_xor(c, 8, 64);
          if (l16 == 0) {
            if (ng == 0) c += boutv;
            float old = __hip_atomic_fetch_add(&g_yacc[sB-511][b], c,
                          __ATOMIC_RELAXED, __HIP_MEMORY_SCOPE_AGENT);
            chk += old;                      // returning add == its own load-back
          }
        }
      }
      #pragma unroll
      for (int reg = 0; reg < 4; ++reg)      // load-backs prove commit
        chk += ld_f16_dc(&h1wr[own + (rl0+reg)*16 + l16]);
      arrive_sum(bl, ng & 15, baseB + 2u*(uint32)sB + 2u, bs_);
    }
  }

  // never true (chk = sum of bounded h/y values); pins the load-backs
  if (chk == -1.25e38f) st_f32_dc(&g_scale[0], 0.f);

  // ---------------- final: wait all B done, output, epoch advance -----------
  waitS(bs_, baseBS + 16u*NGEN);
  if (tid < 64) {
    const int b = Mbase + tid;
    out[b*NPRED + rr_] = ld_f32_dc(&g_yacc[rr_][b]) * ld_f32_dc(&g_scale[b]);
  }
  if (rr_ == 0) {
    waitS(as_, baseAS + 16u*NGEN);
    if (tid == 0) st_u32_dc(&g_sepoch[sid*64], E + 1u);
  }
}

extern "C" void kernel_launch(void* const* d_in, const int* in_sizes, int n_in,
                              void* d_out, int out_size, void* d_ws, size_t ws_size,
                              hipStream_t stream) {
  const float* ctx   = (const float*)d_in[0];
  const float* Wih0  = (const float*)d_in[1];
  const float* Whh0  = (const float*)d_in[2];
  const float* bih0  = (const float*)d_in[3];
  const float* bhh0  = (const float*)d_in[4];
  const float* Wih1  = (const float*)d_in[5];
  const float* Whh1  = (const float*)d_in[6];
  const float* bih1  = (const float*)d_in[7];
  const float* bhh1  = (const float*)d_in[8];
  const float* Wout  = (const float*)d_in[9];
  const float* boutp = (const float*)d_in[10];
  float* out = (float*)d_out;

  hipFuncSetAttribute(reinterpret_cast<const void*>(rnn_persist),
                      hipFuncAttributeMaxDynamicSharedMemorySize, LDS_BYTES);

  void* params[] = {
    (void*)&ctx, (void*)&Wih0, (void*)&Whh0, (void*)&bih0, (void*)&bhh0,
    (void*)&Wih1, (void*)&Whh1, (void*)&bih1, (void*)&bhh1,
    (void*)&Wout, (void*)&boutp, (void*)&out
  };
  hipLaunchCooperativeKernel(reinterpret_cast<void*>(rnn_persist),
                             dim3(NBLK), dim3(NTHR), params, LDS_BYTES, stream);
}

// Round 13
// 3578.827 us; speedup vs baseline: 1.1534x; 1.1534x over previous
//
#include <hip/hip_runtime.h>

typedef unsigned int uint32;
typedef unsigned long long uint64;
typedef _Float16 f16;
typedef _Float16 half8 __attribute__((ext_vector_type(8)));
typedef float floatx4 __attribute__((ext_vector_type(4)));

#define HD    512    // hidden
#define NBAT  256    // batch
#define CTXL  512    // context length
#define NPRED 64     // prediction length
#define NBLK  256
#define NTHR  256
#define NSTR  4      // independent batch stripes (64 rows each)
#define LDS_BYTES (6*16*64*16)   // 98304 B: fragment-linear weights
#define NGEN  575u               // role-intervals per launch

// R24 (BEST, 3563us verified): write-once step-indexed h-buffers + sc0
// consumer reads + sc1 load-back producer protocol. This round (R27) is a
// VERBATIM REVERT to R24 after R25 (+10%: agent-release publish slower than
// load-back), R26 (+16%: hierarchical summary adds a serial hop) both
// regressed. Hop calibration from R26: one MALL hop ~= 1us/gen.
// Protocol: producers store sc1 -> same-address sc1 load-back (proves commit
// at MALL) -> drain -> relaxed sc1 RMW on spread lines. Consumers poll lines
// (16 lanes) then sc0-load operands (write-once addresses -> L2-fill dedup,
// no stale-copy hazard; cross-launch staleness killed by the once-per-launch
// agent acquire fence after init).
__device__ __attribute__((aligned(256))) f16   g_h0s[NGEN+2][NSTR][32][64][16];
__device__ __attribute__((aligned(256))) f16   g_h1s[NGEN+2][NSTR][32][64][16];
__device__ __attribute__((aligned(256))) float g_yacc[NPRED][NBAT];
__device__ __attribute__((aligned(256))) float g_scale[NBAT];
// Per stripe: 16 lines (128B apart) per role; 2 blocks arrive per line per gen.
__device__ __attribute__((aligned(256))) uint32 g_alines[NSTR*16*32];
__device__ __attribute__((aligned(256))) uint32 g_blines[NSTR*16*32];
__device__ __attribute__((aligned(256))) uint32 g_ilines[NSTR*16*32];  // init, 4/line
__device__ __attribute__((aligned(256))) uint32 g_sepoch[NSTR*64];     // launch count

__device__ __forceinline__ float sigm(float x){ return 1.f/(1.f+__expf(-x)); }
__device__ __forceinline__ float tanh_(float x){ return 1.f - 2.f/(__expf(2.f*x)+1.f); }

// ---- device-coherent (sc1, MALL-direct) helpers ----------------------------
__device__ __forceinline__ uint32 ld_u32_dc(const uint32* p){
  return __hip_atomic_load(p, __ATOMIC_RELAXED, __HIP_MEMORY_SCOPE_AGENT);
}
__device__ __forceinline__ void st_u32_dc(uint32* p, uint32 v){
  __hip_atomic_store(p, v, __ATOMIC_RELAXED, __HIP_MEMORY_SCOPE_AGENT);
}
__device__ __forceinline__ void st_u64_dc(uint64* p, uint64 v){
  __hip_atomic_store(p, v, __ATOMIC_RELAXED, __HIP_MEMORY_SCOPE_AGENT);
}
__device__ __forceinline__ float ld_f32_dc(const float* p){
  return __hip_atomic_load(p, __ATOMIC_RELAXED, __HIP_MEMORY_SCOPE_AGENT);
}
__device__ __forceinline__ void st_f32_dc(float* p, float v){
  __hip_atomic_store(p, v, __ATOMIC_RELAXED, __HIP_MEMORY_SCOPE_AGENT);
}
__device__ __forceinline__ float ld_f16_dc(const f16* p){
  unsigned short u = __hip_atomic_load((const unsigned short*)p, __ATOMIC_RELAXED, __HIP_MEMORY_SCOPE_AGENT);
  union { unsigned short u; f16 h; } c; c.u = u; return (float)c.h;
}
__device__ __forceinline__ void st_f16_dc(f16* p, f16 h){
  union { unsigned short u; f16 h; } c; c.h = h;
  __hip_atomic_store((unsigned short*)p, c.u, __ATOMIC_RELAXED, __HIP_MEMORY_SCOPE_AGENT);
}
// ---- sc0 (L1-bypass, L2-FILL) consumer load: write-once addresses only -----
__device__ __forceinline__ void ld_b128_sc0(floatx4* d, const f16* p){
  asm volatile("global_load_dwordx4 %0, %1, off sc0" : "=v"(*d) : "v"(p));
}
#define VM_DRAIN() do { asm volatile("s_waitcnt vmcnt(0)":::"memory"); \
                        __builtin_amdgcn_sched_barrier(0); } while(0)

// Wait until all 16 lines of `lines` reach tgt (wave-0 ballot gather), then
// syncthreads (compiler/memory fence keeping data loads after the poll).
__device__ __forceinline__ void waitl(const uint32* lines, uint32 tgt){
  if (threadIdx.x < 64) {
    const int lane = threadIdx.x;
    const uint32* fp = &lines[(lane & 15)*32];
    for (;;) {
      bool ok = (lane >= 16) || ((int)(ld_u32_dc(fp) - tgt) >= 0);
      if (__ballot(ok) == ~0ull) break;
      __builtin_amdgcn_s_sleep(1);
    }
  }
  __syncthreads();
}
// Arrival: drain this block's stores+load-backs (fence+syncthreads), then one
// relaxed RMW (load-backs already proved data commit at the MALL — R15).
__device__ __forceinline__ void arrive(uint32* lines, int li){
  __builtin_amdgcn_fence(__ATOMIC_RELEASE, "workgroup");
  __syncthreads();
  if (threadIdx.x == 0)
    __hip_atomic_fetch_add(&lines[li*32], 1u, __ATOMIC_RELAXED, __HIP_MEMORY_SCOPE_AGENT);
}
__device__ __forceinline__ void arrive_rel(uint32* lines, int li){  // init only
  __builtin_amdgcn_fence(__ATOMIC_RELEASE, "workgroup");
  __syncthreads();
  if (threadIdx.x == 0)
    __hip_atomic_fetch_add(&lines[li*32], 1u, __ATOMIC_RELEASE, __HIP_MEMORY_SCOPE_AGENT);
}

// Persistent 2-layer GRU + AR decode; 4 independent 64-row stripes.
// Stripe s: blocks 64s..64s+63. rr<32: A (layer 0); rr>=32: B (layer 1).
// Weights in fragment-linear LDS. Region-major h-state:
// addr = region*1024 + row_local*16 + col; step t lives at buffer index t+1.
__global__ __launch_bounds__(NTHR, 1) void rnn_persist(
    const float* __restrict__ ctx,    // [256][512] f32
    const float* __restrict__ Wih0,   // [1536]
    const float* __restrict__ Whh0,   // [1536][512]
    const float* __restrict__ bih0,   // [1536]
    const float* __restrict__ bhh0,   // [1536]
    const float* __restrict__ Wih1,   // [1536][512]
    const float* __restrict__ Whh1,   // [1536][512]
    const float* __restrict__ bih1,   // [1536]
    const float* __restrict__ bhh1,   // [1536]
    const float* __restrict__ Wout,   // [512]
    const float* __restrict__ boutp,  // [1]
    float* __restrict__ out)          // [256][64] f32
{
  extern __shared__ char smem_raw[];
  f16* wlds = (f16*)smem_raw;
  __shared__ float wsum[4];

  const int tid  = threadIdx.x;
  const int bid  = blockIdx.x;
  const int sid  = bid >> 6;         // stripe
  const int rr_  = bid & 63;
  const bool isA = rr_ < 32;
  const int ng   = isA ? rr_ : rr_ - 32;
  const int Mbase = sid * 64;        // batch-row base of stripe
  const int s0    = ng * 16;         // hidden-col base of this block
  const int w    = tid >> 6;
  const int lane = tid & 63;
  const int quad = lane >> 4;
  const int l16  = lane & 15;

  uint32* al = &g_alines[sid*512];
  uint32* bl = &g_blines[sid*512];
  uint32* il = &g_ilines[sid*512];
  const uint32 E = ld_u32_dc(&g_sepoch[sid*64]);
  const uint32 baseA = E * (2u*NGEN);
  const uint32 baseB = E * (2u*NGEN);

  // ---------------- init (stripe-local): scale, zero step-0 states ----------
  {
    const int b = bid;               // block bid handles batch row bid
    float s2 = 0.f;
    for (int k = tid; k < CTXL; k += NTHR) s2 += ctx[b*CTXL + k];
    #pragma unroll
    for (int m = 1; m < 64; m <<= 1) s2 += __shfl_xor(s2, m, 64);
    if (lane == 0) wsum[w] = s2;
    __syncthreads();
    float tot = wsum[0] + wsum[1] + wsum[2] + wsum[3];
    float sc  = fmaxf(fabsf(tot / (float)CTXL), 1e-5f);
    if (tid == 0) st_f32_dc(&g_scale[b], sc);
    // zero h0(-1) and h1(-1) at buffer index 0 (64 blocks x 128 u64 each)
    uint64* z0 = (uint64*)&g_h0s[0][sid][0][0][0];
    uint64* z1 = (uint64*)&g_h1s[0][sid][0][0][0];
    const int off = rr_*128;
    for (int k = tid; k < 128; k += NTHR) {
      st_u64_dc(z0+off+k, 0ull); st_u64_dc(z1+off+k, 0ull);
    }
    if (tid < 64) st_f32_dc(&g_yacc[rr_][Mbase + tid], 0.f);
  }

  // -------- weights -> fragment-linear LDS (f32 -> f16, conflict-free) ------
  {
    const int nfrag = isA ? (3*16*64) : (6*16*64);
    for (int idx = tid; idx < nfrag; idx += NTHR) {
      const int ln = idx & 63;
      const int kc = (idx >> 6) & 15;
      const int mg = idx >> 10;
      const float* Wsrc;
      int g;
      if (isA)            { Wsrc = Whh0; g = mg; }
      else if (mg < 3)    { Wsrc = Wih1; g = mg; }
      else                { Wsrc = Whh1; g = mg - 3; }
      const float* src = Wsrc + (size_t)(g*HD + s0 + (ln & 15))*HD + (ln >> 4)*8 + kc*32;
      f16* dst = wlds + (size_t)idx*8;
      #pragma unroll
      for (int j = 0; j < 8; ++j) dst[j] = (f16)src[j];
    }
  }

  // ---------------- per-thread constants ------------------------------------
  float wi_r=0, wi_z=0, wi_n=0, bi_r, bi_z, bi_n, bh_r, bh_z, bh_n;
  float woutj=0, boutv=0;
  const int jcol = s0 + l16;
  const int mf = w;                  // 4 waves x 16 batch rows = 64 rows
  if (isA) {
    wi_r = Wih0[jcol]; wi_z = Wih0[HD + jcol]; wi_n = Wih0[2*HD + jcol];
    bi_r = bih0[jcol]; bi_z = bih0[HD + jcol]; bi_n = bih0[2*HD + jcol];
    bh_r = bhh0[jcol]; bh_z = bhh0[HD + jcol]; bh_n = bhh0[2*HD + jcol];
  } else {
    bi_r = bih1[jcol]; bi_z = bih1[HD + jcol]; bi_n = bih1[2*HD + jcol];
    bh_r = bhh1[jcol]; bh_z = bhh1[HD + jcol]; bh_n = bhh1[2*HD + jcol];
    woutj = Wout[jcol]; boutv = boutp[0];
  }

  // region-major addressing constants
  const int rl0 = mf*16 + quad*4;    // first local row of my 4 output rows
  const int arl = mf*16 + l16;       // local row of my MFMA A-fragment
  const int own = ng*1024;           // my region base (elements)
  const size_t afrag = (size_t)(quad>>1)*1024 + (size_t)arl*16 + (quad&1)*8;
  const size_t SSTEP = (size_t)NSTR*32*64*16;   // elements per step index

  // strong init barrier (release arrival + agent acquire, once per launch).
  // The acquire fence also invalidates any stale L2 lines of the step-indexed
  // buffers left over from a PREVIOUS launch (write-once is per-launch).
  arrive_rel(il, rr_ & 15);
  waitl(il, E*4u + 4u);
  __builtin_amdgcn_fence(__ATOMIC_ACQUIRE, "agent");
  __syncthreads();

  // preload scale for my 4 output rows
  float scl[4];
  {
    const int bb = Mbase + rl0;
    #pragma unroll
    for (int reg = 0; reg < 4; ++reg) scl[reg] = ld_f32_dc(&g_scale[bb + reg]);
  }

  float chk = 0.f;     // load-back accumulator; guard below is never true
  float hold[4] = {0.f, 0.f, 0.f, 0.f};  // own-slice previous output (registers)

  // ---------------- role loops ----------------------------------------------
  if (isA) {
    const f16* h0base = &g_h0s[0][sid][0][0][0];
    for (int sA = 0; sA < (int)NGEN; ++sA) {
      const int b0 = Mbase + rl0;
      float xv[4];
      if (sA < 512) {                                // hoisted: ctx is read-only
        #pragma unroll
        for (int reg = 0; reg < 4; ++reg)
          xv[reg] = ctx[(b0+reg)*CTXL + sA] / scl[reg];
      }
      waitl(al, baseA + 2u*(uint32)sA);              // own: all A done sA-1
      const f16* hrd = h0base + (size_t)sA*SSTEP;      // h0(sA-1) @ index sA
      f16*       hwr = (f16*)h0base + (size_t)(sA+1)*SSTEP;  // h0(sA)
      const f16* aptr = hrd + afrag;
      union { floatx4 f; half8 h; } av[16];
      #pragma unroll
      for (int kc = 0; kc < 16; ++kc)
        ld_b128_sc0(&av[kc].f, aptr + kc*2048);      // sc0: L2-fill, dedup'd
      if (sA >= 512) {
        waitl(bl, baseB + 2u*(uint32)sA);            // y(sA-512) ready
        #pragma unroll
        for (int reg = 0; reg < 4; ++reg)
          xv[reg] = ld_f32_dc(&g_yacc[sA-512][b0+reg]);
      }
      VM_DRAIN();
      floatx4 ar = {0.f,0.f,0.f,0.f}, az = ar, an_ = ar;
      const f16* fb = wlds + (size_t)lane*8;
      #pragma unroll
      for (int kc = 0; kc < 16; ++kc) {
        const f16* fkc = fb + (size_t)kc*512;
        half8 v;
        v = *(const half8*)(fkc);          ar  = __builtin_amdgcn_mfma_f32_16x16x32_f16(av[kc].h, v, ar,  0,0,0);
        v = *(const half8*)(fkc + 8192);   az  = __builtin_amdgcn_mfma_f32_16x16x32_f16(av[kc].h, v, az,  0,0,0);
        v = *(const half8*)(fkc + 16384);  an_ = __builtin_amdgcn_mfma_f32_16x16x32_f16(av[kc].h, v, an_, 0,0,0);
      }
      #pragma unroll
      for (int reg = 0; reg < 4; ++reg) {
        float hgr = ar[reg] + bh_r, hgz = az[reg] + bh_z, hgn = an_[reg] + bh_n;
        float rg  = sigm(fmaf(xv[reg], wi_r, bi_r) + hgr);
        float zg  = sigm(fmaf(xv[reg], wi_z, bi_z) + hgz);
        float ng_ = tanh_(fmaf(xv[reg], wi_n, bi_n) + rg*hgn);
        f16 hq = (f16)((1.f - zg)*ng_ + zg*hold[reg]);
        st_f16_dc(&hwr[own + (rl0+reg)*16 + l16], hq);
        hold[reg] = (float)hq;                       // carry rounded value
      }
      #pragma unroll
      for (int reg = 0; reg < 4; ++reg)        // load-backs prove commit
        chk += ld_f16_dc(&hwr[own + (rl0+reg)*16 + l16]);
      arrive(al, rr_ & 15);
    }
  } else {
    const f16* h0base = &g_h0s[0][sid][0][0][0];
    const f16* h1base = &g_h1s[0][sid][0][0][0];
    for (int sB = 0; sB < (int)NGEN; ++sB) {
      waitl(al, baseA + 2u*(uint32)(sB+1));          // h0(sB) published
      const f16* a0p = h0base + (size_t)(sB+1)*SSTEP + afrag;   // h0(sB)
      union { floatx4 f; half8 h; } a0v[16], a1v[16];
      #pragma unroll
      for (int kc = 0; kc < 16; ++kc)
        ld_b128_sc0(&a0v[kc].f, a0p + kc*2048);      // sc0: L2-fill
      waitl(bl, baseB + 2u*(uint32)sB);              // own: all B done sB-1
      const f16* a1p = h1base + (size_t)sB*SSTEP + afrag;       // h1(sB-1)
      f16*       h1wr = (f16*)h1base + (size_t)(sB+1)*SSTEP;    // h1(sB)
      const int b0 = Mbase + rl0;
      #pragma unroll
      for (int kc = 0; kc < 16; ++kc)
        ld_b128_sc0(&a1v[kc].f, a1p + kc*2048);      // sc0: L2-fill
      VM_DRAIN();
      floatx4 xr = {0.f,0.f,0.f,0.f}, xz = xr, xn = xr, hr = xr, hz = xr, hn = xr;
      const f16* fb = wlds + (size_t)lane*8;
      #pragma unroll
      for (int kc = 0; kc < 16; ++kc) {
        const f16* fkc = fb + (size_t)kc*512;
        half8 v;
        v = *(const half8*)(fkc);           xr = __builtin_amdgcn_mfma_f32_16x16x32_f16(a0v[kc].h, v, xr, 0,0,0);
        v = *(const half8*)(fkc + 8192);    xz = __builtin_amdgcn_mfma_f32_16x16x32_f16(a0v[kc].h, v, xz, 0,0,0);
        v = *(const half8*)(fkc + 16384);   xn = __builtin_amdgcn_mfma_f32_16x16x32_f16(a0v[kc].h, v, xn, 0,0,0);
      }
      #pragma unroll
      for (int kc = 0; kc < 16; ++kc) {
        const f16* fkc = fb + (size_t)kc*512;
        half8 v;
        v = *(const half8*)(fkc + 24576);   hr = __builtin_amdgcn_mfma_f32_16x16x32_f16(a1v[kc].h, v, hr, 0,0,0);
        v = *(const half8*)(fkc + 32768);   hz = __builtin_amdgcn_mfma_f32_16x16x32_f16(a1v[kc].h, v, hz, 0,0,0);
        v = *(const half8*)(fkc + 40960);   hn = __builtin_amdgcn_mfma_f32_16x16x32_f16(a1v[kc].h, v, hn, 0,0,0);
      }
      #pragma unroll
      for (int reg = 0; reg < 4; ++reg) {
        const int b = b0 + reg;
        float rg  = sigm(xr[reg] + bi_r + hr[reg] + bh_r);
        float zg  = sigm(xz[reg] + bi_z + hz[reg] + bh_z);
        float ng_ = tanh_(xn[reg] + bi_n + rg*(hn[reg] + bh_n));
        float hnew = (1.f - zg)*ng_ + zg*hold[reg];
        f16 hq = (f16)hnew;
        st_f16_dc(&h1wr[own + (rl0+reg)*16 + l16], hq);
        hold[reg] = (float)hq;                       // carry rounded value
        if (sB >= 511) {                     // forecast partials, p = sB-511
          float c = hnew * woutj;
          c += __shfl_xor(c, 1, 64); c += __shfl_xor(c, 2, 64);
          c += __shfl_xor(c, 4, 64); c += __shfl_xor(c, 8, 64);
          if (l16 == 0) {
            if (ng == 0) c += boutv;
            float old = __hip_atomic_fetch_add(&g_yacc[sB-511][b], c,
                          __ATOMIC_RELAXED, __HIP_MEMORY_SCOPE_AGENT);
            chk += old;                      // returning add == its own load-back
          }
        }
      }
      #pragma unroll
      for (int reg = 0; reg < 4; ++reg)      // load-backs prove commit
        chk += ld_f16_dc(&h1wr[own + (rl0+reg)*16 + l16]);
      arrive(bl, ng & 15);
    }
  }

  // never true (chk = sum of bounded h/y values); pins the load-backs
  if (chk == -1.25e38f) st_f32_dc(&g_scale[0], 0.f);

  // ---------------- final: wait all B done, output, epoch advance -----------
  waitl(bl, baseB + 2u*NGEN);
  if (tid < 64) {
    const int b = Mbase + tid;
    out[b*NPRED + rr_] = ld_f32_dc(&g_yacc[rr_][b]) * ld_f32_dc(&g_scale[b]);
  }
  if (rr_ == 0) {
    waitl(al, baseA + 2u*NGEN);
    if (tid == 0) st_u32_dc(&g_sepoch[sid*64], E + 1u);
  }
}

extern "C" void kernel_launch(void* const* d_in, const int* in_sizes, int n_in,
                              void* d_out, int out_size, void* d_ws, size_t ws_size,
                              hipStream_t stream) {
  const float* ctx   = (const float*)d_in[0];
  const float* Wih0  = (const float*)d_in[1];
  const float* Whh0  = (const float*)d_in[2];
  const float* bih0  = (const float*)d_in[3];
  const float* bhh0  = (const float*)d_in[4];
  const float* Wih1  = (const float*)d_in[5];
  const float* Whh1  = (const float*)d_in[6];
  const float* bih1  = (const float*)d_in[7];
  const float* bhh1  = (const float*)d_in[8];
  const float* Wout  = (const float*)d_in[9];
  const float* boutp = (const float*)d_in[10];
  float* out = (float*)d_out;

  hipFuncSetAttribute(reinterpret_cast<const void*>(rnn_persist),
                      hipFuncAttributeMaxDynamicSharedMemorySize, LDS_BYTES);

  void* params[] = {
    (void*)&ctx, (void*)&Wih0, (void*)&Whh0, (void*)&bih0, (void*)&bhh0,
    (void*)&Wih1, (void*)&Whh1, (void*)&bih1, (void*)&bhh1,
    (void*)&Wout, (void*)&boutp, (void*)&out
  };
  hipLaunchCooperativeKernel(reinterpret_cast<void*>(rnn_persist),
                             dim3(NBLK), dim3(NTHR), params, LDS_BYTES, stream);
}

// Round 15
// 3502.285 us; speedup vs baseline: 1.1786x; 1.0219x over previous
//
#include <hip/hip_runtime.h>

typedef unsigned int uint32;
typedef unsigned long long uint64;
typedef _Float16 f16;
typedef _Float16 half8 __attribute__((ext_vector_type(8)));
typedef float floatx4 __attribute__((ext_vector_type(4)));

#define HD    512    // hidden
#define NBAT  256    // batch
#define CTXL  512    // context length
#define NPRED 64     // prediction length
#define NBLK  256
#define NTHR  256
#define NSTR  4      // independent batch stripes (64 rows each)
#define LDS_BYTES (6*16*64*16)   // 98304 B: fragment-linear weights
#define NGEN  575u               // role-intervals per launch

// R24 (BEST, 3563/3578us verified twice): write-once step-indexed h-buffers +
// sc0 consumer reads + sc1 load-back producer protocol. R28 (per-line gated
// loads) FAILED correctness (absmax 0.43 — the broken-read-gating signature;
// 4th variant with that value). This round restores the verified R24 source
// verbatim. Refuted levers on this chip: agent-acquire fences in-loop (R18,
// 2x), agent-release publish (R25, +10%), hierarchical summary (R26, +16%),
// wait fusion (R19, +6%), per-line gating (R28, correctness). Period matches
// the ~4.5-MALL-hop serial floor: latency-bound, not BW/compute-bound.
__device__ __attribute__((aligned(256))) f16   g_h0s[NGEN+2][NSTR][32][64][16];
__device__ __attribute__((aligned(256))) f16   g_h1s[NGEN+2][NSTR][32][64][16];
__device__ __attribute__((aligned(256))) float g_yacc[NPRED][NBAT];
__device__ __attribute__((aligned(256))) float g_scale[NBAT];
// Per stripe: 16 lines (128B apart) per role; 2 blocks arrive per line per gen.
__device__ __attribute__((aligned(256))) uint32 g_alines[NSTR*16*32];
__device__ __attribute__((aligned(256))) uint32 g_blines[NSTR*16*32];
__device__ __attribute__((aligned(256))) uint32 g_ilines[NSTR*16*32];  // init, 4/line
__device__ __attribute__((aligned(256))) uint32 g_sepoch[NSTR*64];     // launch count

__device__ __forceinline__ float sigm(float x){ return 1.f/(1.f+__expf(-x)); }
__device__ __forceinline__ float tanh_(float x){ return 1.f - 2.f/(__expf(2.f*x)+1.f); }

// ---- device-coherent (sc1, MALL-direct) helpers ----------------------------
__device__ __forceinline__ uint32 ld_u32_dc(const uint32* p){
  return __hip_atomic_load(p, __ATOMIC_RELAXED, __HIP_MEMORY_SCOPE_AGENT);
}
__device__ __forceinline__ void st_u32_dc(uint32* p, uint32 v){
  __hip_atomic_store(p, v, __ATOMIC_RELAXED, __HIP_MEMORY_SCOPE_AGENT);
}
__device__ __forceinline__ void st_u64_dc(uint64* p, uint64 v){
  __hip_atomic_store(p, v, __ATOMIC_RELAXED, __HIP_MEMORY_SCOPE_AGENT);
}
__device__ __forceinline__ float ld_f32_dc(const float* p){
  return __hip_atomic_load(p, __ATOMIC_RELAXED, __HIP_MEMORY_SCOPE_AGENT);
}
__device__ __forceinline__ void st_f32_dc(float* p, float v){
  __hip_atomic_store(p, v, __ATOMIC_RELAXED, __HIP_MEMORY_SCOPE_AGENT);
}
__device__ __forceinline__ float ld_f16_dc(const f16* p){
  unsigned short u = __hip_atomic_load((const unsigned short*)p, __ATOMIC_RELAXED, __HIP_MEMORY_SCOPE_AGENT);
  union { unsigned short u; f16 h; } c; c.u = u; return (float)c.h;
}
__device__ __forceinline__ void st_f16_dc(f16* p, f16 h){
  union { unsigned short u; f16 h; } c; c.h = h;
  __hip_atomic_store((unsigned short*)p, c.u, __ATOMIC_RELAXED, __HIP_MEMORY_SCOPE_AGENT);
}
// ---- sc0 (L1-bypass, L2-FILL) consumer load: write-once addresses only -----
__device__ __forceinline__ void ld_b128_sc0(floatx4* d, const f16* p){
  asm volatile("global_load_dwordx4 %0, %1, off sc0" : "=v"(*d) : "v"(p));
}
#define VM_DRAIN() do { asm volatile("s_waitcnt vmcnt(0)":::"memory"); \
                        __builtin_amdgcn_sched_barrier(0); } while(0)

// Wait until all 16 lines of `lines` reach tgt (wave-0 ballot gather), then
// syncthreads (compiler/memory fence keeping data loads after the poll).
__device__ __forceinline__ void waitl(const uint32* lines, uint32 tgt){
  if (threadIdx.x < 64) {
    const int lane = threadIdx.x;
    const uint32* fp = &lines[(lane & 15)*32];
    for (;;) {
      bool ok = (lane >= 16) || ((int)(ld_u32_dc(fp) - tgt) >= 0);
      if (__ballot(ok) == ~0ull) break;
      __builtin_amdgcn_s_sleep(1);
    }
  }
  __syncthreads();
}
// Arrival: drain this block's stores+load-backs (fence+syncthreads), then one
// relaxed RMW (load-backs already proved data commit at the MALL — R15).
__device__ __forceinline__ void arrive(uint32* lines, int li){
  __builtin_amdgcn_fence(__ATOMIC_RELEASE, "workgroup");
  __syncthreads();
  if (threadIdx.x == 0)
    __hip_atomic_fetch_add(&lines[li*32], 1u, __ATOMIC_RELAXED, __HIP_MEMORY_SCOPE_AGENT);
}
__device__ __forceinline__ void arrive_rel(uint32* lines, int li){  // init only
  __builtin_amdgcn_fence(__ATOMIC_RELEASE, "workgroup");
  __syncthreads();
  if (threadIdx.x == 0)
    __hip_atomic_fetch_add(&lines[li*32], 1u, __ATOMIC_RELEASE, __HIP_MEMORY_SCOPE_AGENT);
}

// Persistent 2-layer GRU + AR decode; 4 independent 64-row stripes.
// Stripe s: blocks 64s..64s+63. rr<32: A (layer 0); rr>=32: B (layer 1).
// Weights in fragment-linear LDS. Region-major h-state:
// addr = region*1024 + row_local*16 + col; step t lives at buffer index t+1.
__global__ __launch_bounds__(NTHR, 1) void rnn_persist(
    const float* __restrict__ ctx,    // [256][512] f32
    const float* __restrict__ Wih0,   // [1536]
    const float* __restrict__ Whh0,   // [1536][512]
    const float* __restrict__ bih0,   // [1536]
    const float* __restrict__ bhh0,   // [1536]
    const float* __restrict__ Wih1,   // [1536][512]
    const float* __restrict__ Whh1,   // [1536][512]
    const float* __restrict__ bih1,   // [1536]
    const float* __restrict__ bhh1,   // [1536]
    const float* __restrict__ Wout,   // [512]
    const float* __restrict__ boutp,  // [1]
    float* __restrict__ out)          // [256][64] f32
{
  extern __shared__ char smem_raw[];
  f16* wlds = (f16*)smem_raw;
  __shared__ float wsum[4];

  const int tid  = threadIdx.x;
  const int bid  = blockIdx.x;
  const int sid  = bid >> 6;         // stripe
  const int rr_  = bid & 63;
  const bool isA = rr_ < 32;
  const int ng   = isA ? rr_ : rr_ - 32;
  const int Mbase = sid * 64;        // batch-row base of stripe
  const int s0    = ng * 16;         // hidden-col base of this block
  const int w    = tid >> 6;
  const int lane = tid & 63;
  const int quad = lane >> 4;
  const int l16  = lane & 15;

  uint32* al = &g_alines[sid*512];
  uint32* bl = &g_blines[sid*512];
  uint32* il = &g_ilines[sid*512];
  const uint32 E = ld_u32_dc(&g_sepoch[sid*64]);
  const uint32 baseA = E * (2u*NGEN);
  const uint32 baseB = E * (2u*NGEN);

  // ---------------- init (stripe-local): scale, zero step-0 states ----------
  {
    const int b = bid;               // block bid handles batch row bid
    float s2 = 0.f;
    for (int k = tid; k < CTXL; k += NTHR) s2 += ctx[b*CTXL + k];
    #pragma unroll
    for (int m = 1; m < 64; m <<= 1) s2 += __shfl_xor(s2, m, 64);
    if (lane == 0) wsum[w] = s2;
    __syncthreads();
    float tot = wsum[0] + wsum[1] + wsum[2] + wsum[3];
    float sc  = fmaxf(fabsf(tot / (float)CTXL), 1e-5f);
    if (tid == 0) st_f32_dc(&g_scale[b], sc);
    // zero h0(-1) and h1(-1) at buffer index 0 (64 blocks x 128 u64 each)
    uint64* z0 = (uint64*)&g_h0s[0][sid][0][0][0];
    uint64* z1 = (uint64*)&g_h1s[0][sid][0][0][0];
    const int off = rr_*128;
    for (int k = tid; k < 128; k += NTHR) {
      st_u64_dc(z0+off+k, 0ull); st_u64_dc(z1+off+k, 0ull);
    }
    if (tid < 64) st_f32_dc(&g_yacc[rr_][Mbase + tid], 0.f);
  }

  // -------- weights -> fragment-linear LDS (f32 -> f16, conflict-free) ------
  {
    const int nfrag = isA ? (3*16*64) : (6*16*64);
    for (int idx = tid; idx < nfrag; idx += NTHR) {
      const int ln = idx & 63;
      const int kc = (idx >> 6) & 15;
      const int mg = idx >> 10;
      const float* Wsrc;
      int g;
      if (isA)            { Wsrc = Whh0; g = mg; }
      else if (mg < 3)    { Wsrc = Wih1; g = mg; }
      else                { Wsrc = Whh1; g = mg - 3; }
      const float* src = Wsrc + (size_t)(g*HD + s0 + (ln & 15))*HD + (ln >> 4)*8 + kc*32;
      f16* dst = wlds + (size_t)idx*8;
      #pragma unroll
      for (int j = 0; j < 8; ++j) dst[j] = (f16)src[j];
    }
  }

  // ---------------- per-thread constants ------------------------------------
  float wi_r=0, wi_z=0, wi_n=0, bi_r, bi_z, bi_n, bh_r, bh_z, bh_n;
  float woutj=0, boutv=0;
  const int jcol = s0 + l16;
  const int mf = w;                  // 4 waves x 16 batch rows = 64 rows
  if (isA) {
    wi_r = Wih0[jcol]; wi_z = Wih0[HD + jcol]; wi_n = Wih0[2*HD + jcol];
    bi_r = bih0[jcol]; bi_z = bih0[HD + jcol]; bi_n = bih0[2*HD + jcol];
    bh_r = bhh0[jcol]; bh_z = bhh0[HD + jcol]; bh_n = bhh0[2*HD + jcol];
  } else {
    bi_r = bih1[jcol]; bi_z = bih1[HD + jcol]; bi_n = bih1[2*HD + jcol];
    bh_r = bhh1[jcol]; bh_z = bhh1[HD + jcol]; bh_n = bhh1[2*HD + jcol];
    woutj = Wout[jcol]; boutv = boutp[0];
  }

  // region-major addressing constants
  const int rl0 = mf*16 + quad*4;    // first local row of my 4 output rows
  const int arl = mf*16 + l16;       // local row of my MFMA A-fragment
  const int own = ng*1024;           // my region base (elements)
  const size_t afrag = (size_t)(quad>>1)*1024 + (size_t)arl*16 + (quad&1)*8;
  const size_t SSTEP = (size_t)NSTR*32*64*16;   // elements per step index

  // strong init barrier (release arrival + agent acquire, once per launch).
  // The acquire fence also invalidates any stale L2 lines of the step-indexed
  // buffers left over from a PREVIOUS launch (write-once is per-launch).
  arrive_rel(il, rr_ & 15);
  waitl(il, E*4u + 4u);
  __builtin_amdgcn_fence(__ATOMIC_ACQUIRE, "agent");
  __syncthreads();

  // preload scale for my 4 output rows
  float scl[4];
  {
    const int bb = Mbase + rl0;
    #pragma unroll
    for (int reg = 0; reg < 4; ++reg) scl[reg] = ld_f32_dc(&g_scale[bb + reg]);
  }

  float chk = 0.f;     // load-back accumulator; guard below is never true
  float hold[4] = {0.f, 0.f, 0.f, 0.f};  // own-slice previous output (registers)

  // ---------------- role loops ----------------------------------------------
  if (isA) {
    const f16* h0base = &g_h0s[0][sid][0][0][0];
    for (int sA = 0; sA < (int)NGEN; ++sA) {
      const int b0 = Mbase + rl0;
      float xv[4];
      if (sA < 512) {                                // hoisted: ctx is read-only
        #pragma unroll
        for (int reg = 0; reg < 4; ++reg)
          xv[reg] = ctx[(b0+reg)*CTXL + sA] / scl[reg];
      }
      waitl(al, baseA + 2u*(uint32)sA);              // own: all A done sA-1
      const f16* hrd = h0base + (size_t)sA*SSTEP;      // h0(sA-1) @ index sA
      f16*       hwr = (f16*)h0base + (size_t)(sA+1)*SSTEP;  // h0(sA)
      const f16* aptr = hrd + afrag;
      union { floatx4 f; half8 h; } av[16];
      #pragma unroll
      for (int kc = 0; kc < 16; ++kc)
        ld_b128_sc0(&av[kc].f, aptr + kc*2048);      // sc0: L2-fill, dedup'd
      if (sA >= 512) {
        waitl(bl, baseB + 2u*(uint32)sA);            // y(sA-512) ready
        #pragma unroll
        for (int reg = 0; reg < 4; ++reg)
          xv[reg] = ld_f32_dc(&g_yacc[sA-512][b0+reg]);
      }
      VM_DRAIN();
      floatx4 ar = {0.f,0.f,0.f,0.f}, az = ar, an_ = ar;
      const f16* fb = wlds + (size_t)lane*8;
      #pragma unroll
      for (int kc = 0; kc < 16; ++kc) {
        const f16* fkc = fb + (size_t)kc*512;
        half8 v;
        v = *(const half8*)(fkc);          ar  = __builtin_amdgcn_mfma_f32_16x16x32_f16(av[kc].h, v, ar,  0,0,0);
        v = *(const half8*)(fkc + 8192);   az  = __builtin_amdgcn_mfma_f32_16x16x32_f16(av[kc].h, v, az,  0,0,0);
        v = *(const half8*)(fkc + 16384);  an_ = __builtin_amdgcn_mfma_f32_16x16x32_f16(av[kc].h, v, an_, 0,0,0);
      }
      #pragma unroll
      for (int reg = 0; reg < 4; ++reg) {
        float hgr = ar[reg] + bh_r, hgz = az[reg] + bh_z, hgn = an_[reg] + bh_n;
        float rg  = sigm(fmaf(xv[reg], wi_r, bi_r) + hgr);
        float zg  = sigm(fmaf(xv[reg], wi_z, bi_z) + hgz);
        float ng_ = tanh_(fmaf(xv[reg], wi_n, bi_n) + rg*hgn);
        f16 hq = (f16)((1.f - zg)*ng_ + zg*hold[reg]);
        st_f16_dc(&hwr[own + (rl0+reg)*16 + l16], hq);
        hold[reg] = (float)hq;                       // carry rounded value
      }
      #pragma unroll
      for (int reg = 0; reg < 4; ++reg)        // load-backs prove commit
        chk += ld_f16_dc(&hwr[own + (rl0+reg)*16 + l16]);
      arrive(al, rr_ & 15);
    }
  } else {
    const f16* h0base = &g_h0s[0][sid][0][0][0];
    const f16* h1base = &g_h1s[0][sid][0][0][0];
    for (int sB = 0; sB < (int)NGEN; ++sB) {
      waitl(al, baseA + 2u*(uint32)(sB+1));          // h0(sB) published
      const f16* a0p = h0base + (size_t)(sB+1)*SSTEP + afrag;   // h0(sB)
      union { floatx4 f; half8 h; } a0v[16], a1v[16];
      #pragma unroll
      for (int kc = 0; kc < 16; ++kc)
        ld_b128_sc0(&a0v[kc].f, a0p + kc*2048);      // sc0: L2-fill
      waitl(bl, baseB + 2u*(uint32)sB);              // own: all B done sB-1
      const f16* a1p = h1base + (size_t)sB*SSTEP + afrag;       // h1(sB-1)
      f16*       h1wr = (f16*)h1base + (size_t)(sB+1)*SSTEP;    // h1(sB)
      const int b0 = Mbase + rl0;
      #pragma unroll
      for (int kc = 0; kc < 16; ++kc)
        ld_b128_sc0(&a1v[kc].f, a1p + kc*2048);      // sc0: L2-fill
      VM_DRAIN();
      floatx4 xr = {0.f,0.f,0.f,0.f}, xz = xr, xn = xr, hr = xr, hz = xr, hn = xr;
      const f16* fb = wlds + (size_t)lane*8;
      #pragma unroll
      for (int kc = 0; kc < 16; ++kc) {
        const f16* fkc = fb + (size_t)kc*512;
        half8 v;
        v = *(const half8*)(fkc);           xr = __builtin_amdgcn_mfma_f32_16x16x32_f16(a0v[kc].h, v, xr, 0,0,0);
        v = *(const half8*)(fkc + 8192);    xz = __builtin_amdgcn_mfma_f32_16x16x32_f16(a0v[kc].h, v, xz, 0,0,0);
        v = *(const half8*)(fkc + 16384);   xn = __builtin_amdgcn_mfma_f32_16x16x32_f16(a0v[kc].h, v, xn, 0,0,0);
      }
      #pragma unroll
      for (int kc = 0; kc < 16; ++kc) {
        const f16* fkc = fb + (size_t)kc*512;
        half8 v;
        v = *(const half8*)(fkc + 24576);   hr = __builtin_amdgcn_mfma_f32_16x16x32_f16(a1v[kc].h, v, hr, 0,0,0);
        v = *(const half8*)(fkc + 32768);   hz = __builtin_amdgcn_mfma_f32_16x16x32_f16(a1v[kc].h, v, hz, 0,0,0);
        v = *(const half8*)(fkc + 40960);   hn = __builtin_amdgcn_mfma_f32_16x16x32_f16(a1v[kc].h, v, hn, 0,0,0);
      }
      #pragma unroll
      for (int reg = 0; reg < 4; ++reg) {
        const int b = b0 + reg;
        float rg  = sigm(xr[reg] + bi_r + hr[reg] + bh_r);
        float zg  = sigm(xz[reg] + bi_z + hz[reg] + bh_z);
        float ng_ = tanh_(xn[reg] + bi_n + rg*(hn[reg] + bh_n));
        float hnew = (1.f - zg)*ng_ + zg*hold[reg];
        f16 hq = (f16)hnew;
        st_f16_dc(&h1wr[own + (rl0+reg)*16 + l16], hq);
        hold[reg] = (float)hq;                       // carry rounded value
        if (sB >= 511) {                     // forecast partials, p = sB-511
          float c = hnew * woutj;
          c += __shfl_xor(c, 1, 64); c += __shfl_xor(c, 2, 64);
          c += __shfl_xor(c, 4, 64); c += __shfl_xor(c, 8, 64);
          if (l16 == 0) {
            if (ng == 0) c += boutv;
            float old = __hip_atomic_fetch_add(&g_yacc[sB-511][b], c,
                          __ATOMIC_RELAXED, __HIP_MEMORY_SCOPE_AGENT);
            chk += old;                      // returning add == its own load-back
          }
        }
      }
      #pragma unroll
      for (int reg = 0; reg < 4; ++reg)      // load-backs prove commit
        chk += ld_f16_dc(&h1wr[own + (rl0+reg)*16 + l16]);
      arrive(bl, ng & 15);
    }
  }

  // never true (chk = sum of bounded h/y values); pins the load-backs
  if (chk == -1.25e38f) st_f32_dc(&g_scale[0], 0.f);

  // ---------------- final: wait all B done, output, epoch advance -----------
  waitl(bl, baseB + 2u*NGEN);
  if (tid < 64) {
    const int b = Mbase + tid;
    out[b*NPRED + rr_] = ld_f32_dc(&g_yacc[rr_][b]) * ld_f32_dc(&g_scale[b]);
  }
  if (rr_ == 0) {
    waitl(al, baseA + 2u*NGEN);
    if (tid == 0) st_u32_dc(&g_sepoch[sid*64], E + 1u);
  }
}

extern "C" void kernel_launch(void* const* d_in, const int* in_sizes, int n_in,
                              void* d_out, int out_size, void* d_ws, size_t ws_size,
                              hipStream_t stream) {
  const float* ctx   = (const float*)d_in[0];
  const float* Wih0  = (const float*)d_in[1];
  const float* Whh0  = (const float*)d_in[2];
  const float* bih0  = (const float*)d_in[3];
  const float* bhh0  = (const float*)d_in[4];
  const float* Wih1  = (const float*)d_in[5];
  const float* Whh1  = (const float*)d_in[6];
  const float* bih1  = (const float*)d_in[7];
  const float* bhh1  = (const float*)d_in[8];
  const float* Wout  = (const float*)d_in[9];
  const float* boutp = (const float*)d_in[10];
  float* out = (float*)d_out;

  hipFuncSetAttribute(reinterpret_cast<const void*>(rnn_persist),
                      hipFuncAttributeMaxDynamicSharedMemorySize, LDS_BYTES);

  void* params[] = {
    (void*)&ctx, (void*)&Wih0, (void*)&Whh0, (void*)&bih0, (void*)&bhh0,
    (void*)&Wih1, (void*)&Whh1, (void*)&bih1, (void*)&bhh1,
    (void*)&Wout, (void*)&boutp, (void*)&out
  };
  hipLaunchCooperativeKernel(reinterpret_cast<void*>(rnn_persist),
                             dim3(NBLK), dim3(NTHR), params, LDS_BYTES, stream);
}